// Round 6
// baseline (137.420 us; speedup 1.0000x reference)
//
#include <hip/hip_runtime.h>

// KDE entropy loss, MI355X/gfx950 — fp8 fused GEMM, symmetric pairs once,
// wrapped-diagonal mapping. R13: barrier-free wave-private pipelines.
// R7/R11/R12 all pinned at ~10KC/iter = LDS-phase + MFMA-phase + VALU-phase
// executed SERIALLY under per-iter block lockstep (2 co-resident blocks are
// phase-locked replicas). Fix: 16 waves of 64x16 tiles, A in regs (direct
// global loads, once), B staged to wave-PRIVATE 4KB LDS regions (dbuf 8KB),
// counted vmcnt(1) self-sync, NO __syncthreads in the k-loop -> waves
// drift and phases overlap. B frag reads 4KB/wave-iter (read once, reused
// x4 row-tiles). Bank fix: involution kbyte ^= (col&7)<<4 on BOTH staging
// global source and ds_read addr. 16x16x128 fragment layouts = R12-verified.
// ws: [0,4MiB) Xn fp8 [16384][256]; [4MiB,+64KiB) density f32; then ticket u32.

#define NROWS 16384
#define KDIM 256            // bytes per fp8 row
#define NTILE 128
#define NT (NROWS / NTILE)  // 128 tile rows
#define NSTRIP 4
#define TOTAL_BLOCKS (NT * NSTRIP)  // 512 blocks of 1024 thr; 1/CU (128KB LDS)

// sqrt(5 * log2(e)): folded into both operands -> sim scaled by 5*log2(e),
// so kernel = exp2(sim_scaled) = exp(5*sim).
#define SQRT_KLOG2E 2.68579577857f

#define SMEM_BYTES (16 * 8192)  // 128 KiB: per-wave private 2x4KB B dbuf

typedef int i32x4_t __attribute__((ext_vector_type(4)));
typedef int i32x8_t __attribute__((ext_vector_type(8)));
typedef float f32x2_t __attribute__((ext_vector_type(2)));
typedef float f32x4_t __attribute__((ext_vector_type(4)));
typedef __attribute__((address_space(1))) const void global_cvoid_t;
typedef __attribute__((address_space(3))) void lds_void_t;

#if __has_builtin(__builtin_amdgcn_exp2f)
#define EXP2(x) __builtin_amdgcn_exp2f(x)
#else
#define EXP2(x) exp2f(x)
#endif

// Counted vmcnt wait; memory clobber pins memory ops on their side.
#define WAITVM(n) asm volatile("s_waitcnt vmcnt(" #n ")" ::: "memory")

union frag32 { i32x8_t v8; i32x4_t v4[2]; };  // 32B/lane MFMA operand

// One wave per row: sqrt(5log2e)/max(||x||,eps), fp8 e4m3 out; zero density+ticket.
__global__ __launch_bounds__(256)
void kde_normalize(const float* __restrict__ X, unsigned int* __restrict__ Xn8,
                   float* __restrict__ density, unsigned int* __restrict__ ticket) {
  const int wave = threadIdx.x >> 6;
  const int lane = threadIdx.x & 63;
  const int row = blockIdx.x * 4 + wave;
  const float4 v = ((const float4*)(X + (size_t)row * KDIM))[lane];
  float ss = v.x * v.x + v.y * v.y + v.z * v.z + v.w * v.w;
  ss += __shfl_xor(ss, 1);
  ss += __shfl_xor(ss, 2);
  ss += __shfl_xor(ss, 4);
  ss += __shfl_xor(ss, 8);
  ss += __shfl_xor(ss, 16);
  ss += __shfl_xor(ss, 32);
  const float scale = SQRT_KLOG2E / fmaxf(sqrtf(ss), 1e-12f);
  int p = 0;
  p = __builtin_amdgcn_cvt_pk_fp8_f32(v.x * scale, v.y * scale, p, false);
  p = __builtin_amdgcn_cvt_pk_fp8_f32(v.z * scale, v.w * scale, p, true);
  Xn8[(size_t)row * 64 + lane] = (unsigned int)p;
  if (threadIdx.x < 4) density[blockIdx.x * 4 + threadIdx.x] = 0.0f;
  if (blockIdx.x == 0 && threadIdx.x == 0) *ticket = 0u;
}

// Block (bi, s): row tile bi; J = (bi+t) mod 128 for t in [s*16, s*16+16)
// (+ t=64 for s==0, bi<64 — dispatched first). Each unordered tile pair
// once. 16 waves: wave = (rg 0..1)*8 + (cg 0..7); wave tile = 64 rows
// (rg*64, A in regs) x 16 cols (cg*16, B from private LDS).
// Per tile: 2 x mfma-K chunks (16x16x128), B frag read once, reused over
// 4 row-tiles -> 8 MFMA/wave-tile, 4 ds_read_b128/wave-tile.
//
// Wave-private k-loop (NO block barrier):
//   iter k: [fence] stage B(k+1) -> own sbuf (4 global_load_lds)
//           ds_read B(k) frags from own rbuf; 8 MFMA; epilogue (exp2,
//           rowsums in regs, colsum global atomic — fire-and-forget)
//           vmcnt(1): prior-iter atomic + this iter's 4 stages retired
//           (in-order count), own atomic may stay in flight.
// B region [c=0..15][kbyte 0..255] with involution kbyte^=(c&7)<<4 on both
// sides: staging issue i, lane l: LDS slot i*1024+l*16 = [c=i*4+(l>>4)]
// [kbyte'=(l&15)*16] <- global (J*128+cg*16+c)*256 + ((l&15)^(c&7))*16.
// ds_read (kq,p): addr = c*256 + ((kq*128+lg*32+p*16)^((c&7)<<4)) ->
// bank = (lg*8+p*4)^((c&7)*4): 2-way (free).
// Fragment layouts (R12 harness-verified): A/B operand lane (idx=lane&15,
// q=lane>>4): row idx, K[kq*128+q*32,+32). C/D: col=lane&15, row=q*4+reg.
__global__ __launch_bounds__(1024, 4)
void kde_gemm(const unsigned char* __restrict__ Xn8, float* __restrict__ density,
              unsigned int* __restrict__ ticket, float* __restrict__ out) {
  extern __shared__ char smem[];

  const int tid = threadIdx.x;
  const int wave = tid >> 6;   // 0..15
  const int lane = tid & 63;
  const int l16 = lane & 15;
  const int lg = lane >> 4;    // K-quarter / C-row-group
  const int rg = wave >> 3;    // row group 0..1 (64 rows each)
  const int cg = wave & 7;     // col group 0..7 (16 cols each)
  const int bi = blockIdx.x;
  const int s = blockIdx.y;
  const int t0 = s * 16;
  const int nt = (s == 0 && bi < NT / 2) ? 17 : 16;
  const char* Xb = (const char*)Xn8;

  char* my0 = smem + wave * 8192;  // private B buffer 0 (4 KB)
  char* my1 = my0 + 4096;          // private B buffer 1 (4 KB)

  // ---- A fragments: direct global->VGPR, once. 64 VGPR. ----
  frag32 areg[4][2];  // [row-tile rt][K-chunk kq]
  {
    const size_t abase =
        (size_t)(bi * NTILE + rg * 64 + l16) * KDIM + lg * 32;
#pragma unroll
    for (int rt = 0; rt < 4; rt++)
#pragma unroll
      for (int kq = 0; kq < 2; kq++)
#pragma unroll
        for (int p = 0; p < 2; p++)
          areg[rt][kq].v4[p] = *(const i32x4_t*)(Xb + abase +
              (size_t)rt * 16 * KDIM + kq * 128 + p * 16);
  }

  // ---- per-lane staging source offsets (within a J-tile) ----
  int stofs[4];
#pragma unroll
  for (int i = 0; i < 4; i++) {
    const int c = i * 4 + lg;
    stofs[i] = (cg * 16 + c) * KDIM + ((l16 ^ (c & 7)) * 16);
  }

#define STAGEB(J, dst)                                                    \
  {                                                                       \
    const size_t jb = (size_t)(J) * (NTILE * KDIM);                       \
    _Pragma("unroll")                                                     \
    for (int i = 0; i < 4; i++)                                           \
      __builtin_amdgcn_global_load_lds(                                   \
          (global_cvoid_t*)(Xb + jb + stofs[i]),                          \
          (lds_void_t*)((dst) + i * 1024), 16, 0, 0);                     \
  }

  // ---- swizzled B-frag read offsets ----
  int rdofs[2][2];
#pragma unroll
  for (int kq = 0; kq < 2; kq++)
#pragma unroll
    for (int p = 0; p < 2; p++)
      rdofs[kq][p] =
          l16 * 256 + ((kq * 128 + lg * 32 + p * 16) ^ ((l16 & 7) << 4));

  STAGEB((bi + t0) & (NT - 1), my0);  // B(0)
  WAITVM(0);                          // A + B(0) landed

  f32x2_t rs2[8];  // rowsums: [rt*2 + jpair], packed
#pragma unroll
  for (int r = 0; r < 8; r++) rs2[r] = (f32x2_t)0.0f;

  for (int k = 0; k < nt; ++k) {
    const int t = (k == 16) ? 64 : (t0 + k);
    const int J = (bi + t) & (NT - 1);
    char* rbuf = (k & 1) ? my1 : my0;  // B(k): retired at last WAITVM
    char* sbuf = (k & 1) ? my0 : my1;  // own buffer, last read iter k-1
    const bool pre = (k + 1 < nt);

    asm volatile("" ::: "memory");  // pin stage issue after prior-iter reads
    if (pre) {
      const int tn = (k + 1 == 16) ? 64 : (t0 + k + 1);
      STAGEB((bi + tn) & (NT - 1), sbuf);
    }

    f32x4_t acc[4];
#pragma unroll
    for (int rt = 0; rt < 4; rt++) acc[rt] = (f32x4_t)0.0f;

#pragma unroll
    for (int kq = 0; kq < 2; kq++) {
      frag32 bf;
      bf.v4[0] = *(const i32x4_t*)(rbuf + rdofs[kq][0]);
      bf.v4[1] = *(const i32x4_t*)(rbuf + rdofs[kq][1]);
#pragma unroll
      for (int rt = 0; rt < 4; rt++)
        acc[rt] = __builtin_amdgcn_mfma_scale_f32_16x16x128_f8f6f4(
            areg[rt][kq].v8, bf.v8, acc[rt], 0, 0, 0, 127, 0, 127);
    }

    // Epilogue: e = exp2(sim_scaled) = exp(5*sim). Lane's 16 e's are all
    // col cg*16+l16, rows rg*64 + rt*16 + lg*4 + j.
    f32x2_t cacc = (f32x2_t)0.0f;
#pragma unroll
    for (int rt = 0; rt < 4; rt++) {
      f32x2_t e01, e23;
      e01.x = EXP2(acc[rt][0]);
      e01.y = EXP2(acc[rt][1]);
      e23.x = EXP2(acc[rt][2]);
      e23.y = EXP2(acc[rt][3]);
      rs2[rt * 2] += e01;      // v_pk_add_f32
      rs2[rt * 2 + 1] += e23;
      cacc += e01;
      cacc += e23;
    }

    if (t != 0) {  // diagonal tile (t=0): rowsum only
      float cs = cacc.x + cacc.y;
      cs += __shfl_xor(cs, 16);  // reduce over lg -> 64-row colsum
      cs += __shfl_xor(cs, 32);
      if (lg == 0) atomicAdd(&density[J * NTILE + cg * 16 + l16], cs);
      if (pre) WAITVM(1);  // [prior atomic][stage x4][own atomic] -> drain 5 oldest
    } else {
      if (pre) WAITVM(0);  // k==0, no atomics yet: just the 4 stages
    }
  }
#undef STAGEB

  // Row epilogue: reduce each of the 16 rowsums over l16 (cols), one
  // atomic instr per value (lanes l16==0, lg=0..3 -> 4 rows each).
#pragma unroll
  for (int idx = 0; idx < 16; idx++) {
    float v = rs2[idx >> 1][idx & 1];
    v += __shfl_xor(v, 1);
    v += __shfl_xor(v, 2);
    v += __shfl_xor(v, 4);
    v += __shfl_xor(v, 8);
    if (l16 == 0) {
      const int rt = idx >> 2, j = idx & 3;
      atomicAdd(&density[bi * NTILE + rg * 64 + rt * 16 + lg * 4 + j], v);
    }
  }

  // Ticket: last finished block computes the entropy (saves 2 launches).
  __syncthreads();  // all waves' atomics issued & drained (vmcnt(0) at barrier)
  if (tid == 0) {
    __threadfence();
    ((volatile unsigned int*)smem)[0] = atomicAdd(ticket, 1u);
  }
  __syncthreads();
  if (((volatile unsigned int*)smem)[0] == TOTAL_BLOCKS - 1) {
    __threadfence();
    float ssum = 0.0f;
    for (int i = tid; i < NROWS; i += 1024) {
      const float d = __hip_atomic_load(&density[i], __ATOMIC_RELAXED,
                                        __HIP_MEMORY_SCOPE_AGENT);
      ssum += logf(d + 1e-9f);
    }
    ssum += __shfl_xor(ssum, 1);
    ssum += __shfl_xor(ssum, 2);
    ssum += __shfl_xor(ssum, 4);
    ssum += __shfl_xor(ssum, 8);
    ssum += __shfl_xor(ssum, 16);
    ssum += __shfl_xor(ssum, 32);
    float* red = ((float*)smem) + 16;
    if (lane == 0) red[wave] = ssum;
    __syncthreads();
    if (tid == 0) {
      float tot = 0.0f;
      for (int w = 0; w < 16; w++) tot += red[w];
      out[0] = -tot / (float)NROWS;
    }
  }
}

extern "C" void kernel_launch(void* const* d_in, const int* in_sizes, int n_in,
                              void* d_out, int out_size, void* d_ws, size_t ws_size,
                              hipStream_t stream) {
  const float* X = (const float*)d_in[0];
  float* out = (float*)d_out;
  char* ws = (char*)d_ws;
  unsigned int* Xn8 = (unsigned int*)ws;
  float* density = (float*)(ws + (size_t)NROWS * KDIM);
  unsigned int* ticket = (unsigned int*)(density + NROWS);

  hipFuncSetAttribute((const void*)kde_gemm,
                      hipFuncAttributeMaxDynamicSharedMemorySize, SMEM_BYTES);

  kde_normalize<<<NROWS / 4, 256, 0, stream>>>(X, Xn8, density, ticket);
  kde_gemm<<<dim3(NT, NSTRIP), 1024, SMEM_BYTES, stream>>>(
      (const unsigned char*)ws, density, ticket, out);
}

// Round 7
// 136.572 us; speedup vs baseline: 1.0062x; 1.0062x over previous
//
#include <hip/hip_runtime.h>

// KDE entropy loss, MI355X/gfx950 — fp8 fused GEMM, symmetric pairs once,
// wrapped-diagonal mapping. R14: serial pipe-sum model (fits R7/R12/R13:
// LDS 3.5K + MFMA 2.2K + VALU ~2.5K + drain ~1K = 10K cy/iter) says the
// largest term is LDS frag-read amplification (4 row-wave-groups re-read
// each B fragment). Fix: 4 waves of 64x64 tiles (256-thr block, same 128^2
// block tile): B frag reads halve (192KB vs 320KB per CU-iter), 16 MFMA per
// 16 ds_reads (was 8), and each SIMD hosts 1 wave from EACH resident block
// (cross-block overlap during barrier drains). All verified R7 pieces kept:
// chunk layout, staging, pair mapping, in-loop colsum atomics, 1 barrier/iter.
// ws: [0,4MiB) Xn fp8 [16384][256]; [4MiB,+64KiB) density f32; then ticket u32.

#define NROWS 16384
#define KDIM 256            // bytes per fp8 row
#define NTILE 128
#define NT (NROWS / NTILE)  // 128 tile rows
#define NSTRIP 4
#define TOTAL_BLOCKS (NT * NSTRIP)  // 512 blocks of 256 thr = exactly 2 per CU

// sqrt(5 * log2(e)): folded into both operands -> sim scaled by 5*log2(e),
// so kernel = exp2(sim_scaled) = exp(5*sim).
#define SQRT_KLOG2E 2.68579577857f

typedef int i32x4_t __attribute__((ext_vector_type(4)));
typedef int i32x8_t __attribute__((ext_vector_type(8)));
typedef float f32x2_t __attribute__((ext_vector_type(2)));
typedef float f32x16_t __attribute__((ext_vector_type(16)));
typedef __attribute__((address_space(1))) const void global_cvoid_t;
typedef __attribute__((address_space(3))) void lds_void_t;

#if __has_builtin(__builtin_amdgcn_exp2f)
#define EXP2(x) __builtin_amdgcn_exp2f(x)
#else
#define EXP2(x) exp2f(x)
#endif

union frag8 { i32x8_t v8; i32x4_t v4[2]; };

// One wave per row: sqrt(5log2e)/max(||x||,eps), fp8 e4m3 out; zero density+ticket.
__global__ __launch_bounds__(256)
void kde_normalize(const float* __restrict__ X, unsigned int* __restrict__ Xn8,
                   float* __restrict__ density, unsigned int* __restrict__ ticket) {
  const int wave = threadIdx.x >> 6;
  const int lane = threadIdx.x & 63;
  const int row = blockIdx.x * 4 + wave;
  const float4 v = ((const float4*)(X + (size_t)row * KDIM))[lane];
  float ss = v.x * v.x + v.y * v.y + v.z * v.z + v.w * v.w;
  ss += __shfl_xor(ss, 1);
  ss += __shfl_xor(ss, 2);
  ss += __shfl_xor(ss, 4);
  ss += __shfl_xor(ss, 8);
  ss += __shfl_xor(ss, 16);
  ss += __shfl_xor(ss, 32);
  const float scale = SQRT_KLOG2E / fmaxf(sqrtf(ss), 1e-12f);
  int p = 0;
  p = __builtin_amdgcn_cvt_pk_fp8_f32(v.x * scale, v.y * scale, p, false);
  p = __builtin_amdgcn_cvt_pk_fp8_f32(v.z * scale, v.w * scale, p, true);
  Xn8[(size_t)row * 64 + lane] = (unsigned int)p;
  if (threadIdx.x < 4) density[blockIdx.x * 4 + threadIdx.x] = 0.0f;
  if (blockIdx.x == 0 && threadIdx.x == 0) *ticket = 0u;
}

// Block (bi, s): row tile bi; J = (bi+t) mod 128 for t in [s*16, s*16+16)
// (+ t=64 for s==0, bi<64 — dispatched first so the 17-iter blocks start
// earliest). Each unordered tile pair once. 4 waves 2x2 over 128x128; wave =
// 64x64 = 2x2 MFMA-tiles of 32x32 x 4 K-chunks (32x32x64 fp8, scale=1 ->
// exact e4m3). A in registers (64 VGPR); B double-buffers in 64 KB LDS;
// 1 barrier/iter; in-loop global colsum atomics (measured free, R8/R10).
__global__ __launch_bounds__(256, 2)
void kde_gemm(const unsigned char* __restrict__ Xn8, float* __restrict__ density,
              unsigned int* __restrict__ ticket, float* __restrict__ out) {
  extern __shared__ char smem[];
  char* buf0 = smem;           // 32 KB
  char* buf1 = smem + 32768;   // 32 KB

  const int tid = threadIdx.x;
  const int wave = tid >> 6;   // 0..3
  const int lane = tid & 63;
  const int wr2 = wave >> 1;   // row half 0..1 (64 rows each)
  const int wc2 = wave & 1;    // col half 0..1 (64 cols each)
  const int m32 = lane & 31;
  const int h = lane >> 5;
  const int bi = blockIdx.x;
  const int s = blockIdx.y;
  const int t0 = s * 16;
  const int nt = (s == 0 && bi < NT / 2) ? 17 : 16;
  const char* Xb = (const char*)Xn8;

  // Chunk c = rt*8 + kb*2 + hh: lane holds M[rt*32+m32][kb*64+h*32+hh*16 ..+15]
  // (identical layout to R7's verified kernel; 8 chunks per wave now).
#define STAGE(base_row, dst)                                                      \
  for (int c = wave; c < 32; c += 4) {                                            \
    const int rt = c >> 3, kb = (c >> 1) & 3, hh = c & 1;                         \
    const size_t gofs =                                                           \
        (size_t)((base_row) + rt * 32 + m32) * KDIM + kb * 64 + h * 32 + hh * 16; \
    __builtin_amdgcn_global_load_lds((global_cvoid_t*)(Xb + gofs),                \
                                     (lds_void_t*)((dst) + c * 1024), 16, 0, 0);  \
  }

  STAGE(bi * NTILE, buf0);                      // A tile -> buf0
  STAGE(((bi + t0) & (NT - 1)) * NTILE, buf1);  // B(0)   -> buf1
  __syncthreads();  // both landed (vmcnt drained at barrier)

  // A fragments -> registers: this wave's 64 rows, full K (64 VGPRs).
  frag8 areg[2][4];  // [row-tile rt][K-chunk kb]
#pragma unroll
  for (int rt = 0; rt < 2; rt++)
#pragma unroll
    for (int kb = 0; kb < 4; kb++) {
      const char* pa =
          buf0 + (((wr2 * 2 + rt) * 8) + kb * 2) * 1024 + lane * 16;
      areg[rt][kb].v4[0] = *(const i32x4_t*)pa;
      areg[rt][kb].v4[1] = *(const i32x4_t*)(pa + 1024);
    }
  __syncthreads();  // all waves done reading A from buf0

  f32x2_t rs2[2][8];  // rowsums per row-tile, packed pairs
#pragma unroll
  for (int rt = 0; rt < 2; rt++)
#pragma unroll
    for (int r = 0; r < 8; r++) rs2[rt][r] = (f32x2_t)0.0f;

  for (int k = 0; k < nt; ++k) {
    const int t = (k == 16) ? 64 : (t0 + k);
    const int J = (bi + t) & (NT - 1);
    char* rbuf = (k & 1) ? buf0 : buf1;  // B(k): landed at last barrier
    char* sbuf = (k & 1) ? buf1 : buf0;  // free since last barrier

    if (k + 1 < nt) {
      const int tn = (k + 1 == 16) ? 64 : (t0 + k + 1);
      STAGE(((bi + tn) & (NT - 1)) * NTILE, sbuf);
    }

    f32x16_t acc[2][2];  // [rt][ct]
#pragma unroll
    for (int rt = 0; rt < 2; rt++)
#pragma unroll
      for (int ct = 0; ct < 2; ct++) acc[rt][ct] = (f32x16_t)0.0f;

#pragma unroll
    for (int kb = 0; kb < 4; ++kb) {
      frag8 bf[2];
#pragma unroll
      for (int ct = 0; ct < 2; ct++) {
        const char* pb =
            rbuf + (((wc2 * 2 + ct) * 8) + kb * 2) * 1024 + lane * 16;
        bf[ct].v4[0] = *(const i32x4_t*)pb;
        bf[ct].v4[1] = *(const i32x4_t*)(pb + 1024);
      }
#pragma unroll
      for (int rt = 0; rt < 2; rt++)
#pragma unroll
        for (int ct = 0; ct < 2; ct++)
          acc[rt][ct] = __builtin_amdgcn_mfma_scale_f32_32x32x64_f8f6f4(
              areg[rt][kb].v8, bf[ct].v8, acc[rt][ct], 0, 0, 0, 127, 0, 127);
    }

    // Epilogue: e = exp2(sim_scaled) = exp(5*sim). Rowsums in regs across k
    // (packed adds); colsums scattered now (in-loop atomics, measured free).
    // C/D: col = m32, row (within 32-tile) = (r&3) + 8*(r>>2) + 4*h.
#pragma unroll
    for (int ct = 0; ct < 2; ct++) {
      f32x2_t c2 = (f32x2_t)0.0f;
#pragma unroll
      for (int rt = 0; rt < 2; rt++)
#pragma unroll
        for (int r2 = 0; r2 < 8; r2++) {
          f32x2_t e;
          e.x = EXP2(acc[rt][ct][2 * r2]);
          e.y = EXP2(acc[rt][ct][2 * r2 + 1]);
          rs2[rt][r2] += e;  // v_pk_add_f32
          c2 += e;
        }
      if (t != 0) {  // diagonal tile (t=0): rowsum only
        float cs = c2.x + c2.y;
        cs += __shfl_xor(cs, 32);  // combine h halves -> full 128-row colsum half
        if (h == 0)  // 2 atomics/col (wr2=0,1 waves)
          atomicAdd(&density[J * NTILE + wc2 * 64 + ct * 32 + m32], cs);
      }
    }

    __syncthreads();  // B(k+1) landed; all waves done reading rbuf
  }

  // Row epilogue: reduce over 32 cols (m32), scatter; 2 atomics/row (wc2=0,1).
#pragma unroll
  for (int rt = 0; rt < 2; rt++)
#pragma unroll
    for (int r = 0; r < 16; r++) {
      float v = rs2[rt][r >> 1][r & 1];
      v += __shfl_xor(v, 1);
      v += __shfl_xor(v, 2);
      v += __shfl_xor(v, 4);
      v += __shfl_xor(v, 8);
      v += __shfl_xor(v, 16);
      if (m32 == 0) {
        const int row = bi * NTILE + wr2 * 64 + rt * 32 +
                        (r & 3) + 8 * (r >> 2) + 4 * h;
        atomicAdd(&density[row], v);
      }
    }
#undef STAGE

  // Ticket: last finished block computes the entropy (saves 2 launches).
  __syncthreads();  // all waves' atomics issued & drained (vmcnt(0) at barrier)
  if (tid == 0) {
    __threadfence();
    ((volatile unsigned int*)smem)[0] = atomicAdd(ticket, 1u);
  }
  __syncthreads();
  if (((volatile unsigned int*)smem)[0] == TOTAL_BLOCKS - 1) {
    __threadfence();
    float ssum = 0.0f;
    for (int i = tid; i < NROWS; i += 256) {
      const float d = __hip_atomic_load(&density[i], __ATOMIC_RELAXED,
                                        __HIP_MEMORY_SCOPE_AGENT);
      ssum += logf(d + 1e-9f);
    }
    ssum += __shfl_xor(ssum, 1);
    ssum += __shfl_xor(ssum, 2);
    ssum += __shfl_xor(ssum, 4);
    ssum += __shfl_xor(ssum, 8);
    ssum += __shfl_xor(ssum, 16);
    ssum += __shfl_xor(ssum, 32);
    float* red = ((float*)smem) + 16;
    if (lane == 0) red[wave] = ssum;
    __syncthreads();
    if (tid == 0) {
      float tot = 0.0f;
      for (int w = 0; w < 4; w++) tot += red[w];
      out[0] = -tot / (float)NROWS;
    }
  }
}

extern "C" void kernel_launch(void* const* d_in, const int* in_sizes, int n_in,
                              void* d_out, int out_size, void* d_ws, size_t ws_size,
                              hipStream_t stream) {
  const float* X = (const float*)d_in[0];
  float* out = (float*)d_out;
  char* ws = (char*)d_ws;
  unsigned int* Xn8 = (unsigned int*)ws;
  float* density = (float*)(ws + (size_t)NROWS * KDIM);
  unsigned int* ticket = (unsigned int*)(density + NROWS);

  hipFuncSetAttribute((const void*)kde_gemm,
                      hipFuncAttributeMaxDynamicSharedMemorySize, 65536);

  kde_normalize<<<NROWS / 4, 256, 0, stream>>>(X, Xn8, density, ticket);
  kde_gemm<<<dim3(NT, NSTRIP), 256, 65536, stream>>>((const unsigned char*)ws,
                                                     density, ticket, out);
}